// Round 1
// 1126.990 us; speedup vs baseline: 1.5670x; 1.5670x over previous
//
#include <hip/hip_runtime.h>
#include <hip/hip_bf16.h>
#include <stdint.h>

// Inputs may be float32 OR bf16 (detected at runtime on-device); internal
// canonical dtype is bf16; compute in fp32; output emitted in detected dtype.
typedef __bf16 bf16_t;
typedef __bf16 bf16x8 __attribute__((ext_vector_type(8)));
typedef float  f32x4  __attribute__((ext_vector_type(4)));

__device__ __forceinline__ f32x4 mfma16(bf16x8 a, bf16x8 b, f32x4 c) {
    // D[row=quad*4+r][col=lane&15]; A[row=lane&15][k=quad*8+j]; B[k=quad*8+j][col=lane&15]
    return __builtin_amdgcn_mfma_f32_16x16x32_bf16(a, b, c, 0, 0, 0);
}

__device__ __forceinline__ float ldv(const void* p, long i, int fp32mode) {
    return fp32mode ? ((const float*)p)[i] : (float)((const bf16_t*)p)[i];
}

// ---------------------------------------------------------------- dtype detect
__global__ __launch_bounds__(256)
void detect_dtype(const void* __restrict__ x, int* __restrict__ flag) {
    __shared__ int cnt;
    if (threadIdx.x == 0) cnt = 0;
    __syncthreads();
    const bf16_t* p = (const bf16_t*)x;
    int local = 0;
    for (int i = threadIdx.x; i < 4096; i += 256) {
        const float v = (float)p[i];
        if (!(fabsf(v) < 1e6f)) local++;   // catches NaN too
    }
    atomicAdd(&cnt, local);
    __syncthreads();
    if (threadIdx.x == 0) { flag[0] = (cnt >= 16) ? 1 : 0; flag[1] = 0; }
}

// ---------------------------------------------------------------- convert-transpose (batched)
__global__ __launch_bounds__(256)
void transpose_cvt(const void* __restrict__ in, bf16_t* __restrict__ out,
                   int R, int C, const int* __restrict__ flagp) {
    __shared__ bf16_t t[32][33];
    const int mode = *flagp;
    const long zi = (long)blockIdx.z * R * C;
    const int c0 = blockIdx.x * 32;
    const int r0 = blockIdx.y * 32;
    const int x  = threadIdx.x;
    const int y0 = threadIdx.y;
    for (int yy = y0; yy < 32; yy += 8)
        t[yy][x] = (bf16_t)ldv(in, zi + (long)(r0 + yy) * C + c0 + x, mode);
    __syncthreads();
    for (int yy = y0; yy < 32; yy += 8)
        out[zi + (long)(c0 + yy) * R + r0 + x] = t[x][yy];
}

// ---------------------------------------------------------------- wv permuted transpose
// W2T[e][h*768+k] = wv[k][h*768+e]   (both ld 9216)
__global__ __launch_bounds__(256)
void transpose_wv(const void* __restrict__ in, bf16_t* __restrict__ out,
                  const int* __restrict__ flagp) {
    __shared__ bf16_t t[32][33];
    const int mode = *flagp;
    const int h  = blockIdx.z;
    const int e0 = blockIdx.x * 32;
    const int k0 = blockIdx.y * 32;
    const int x  = threadIdx.x;
    const int y0 = threadIdx.y;
    for (int yy = y0; yy < 32; yy += 8)
        t[yy][x] = (bf16_t)ldv(in, (long)(k0 + yy) * 9216 + h * 768 + e0 + x, mode);
    __syncthreads();
    for (int yy = y0; yy < 32; yy += 8)
        out[(long)(e0 + yy) * 9216 + h * 768 + k0 + x] = t[x][yy];
}

// ---------------------------------------------------------------- bv head-sum
__global__ __launch_bounds__(256)
void bvsum_k(const void* __restrict__ bv, float* __restrict__ out,
             const int* __restrict__ flagp) {
    const int mode = *flagp;
    const int e = blockIdx.x * 256 + threadIdx.x;
    if (e < 768) {
        float s = 0.f;
#pragma unroll
        for (int h = 0; h < 12; ++h) s += ldv(bv, h * 768 + e, mode);
        out[e] = s;
    }
}

// ---------------------------------------------------------------- layernorm (768 cols)
__global__ __launch_bounds__(256)
void ln768(const void* __restrict__ in, bf16_t* __restrict__ out,
           const void* __restrict__ gam, const void* __restrict__ bet,
           const int* __restrict__ dmodep, const int* __restrict__ pmodep) {
    __shared__ float rs[256], rq[256];
    const int dm = *dmodep, pm = *pmodep;
    const long base = (long)blockIdx.x * 768;
    const int tid = threadIdx.x;
    float v[3];
    float s = 0.f, q = 0.f;
#pragma unroll
    for (int i = 0; i < 3; ++i) {
        v[i] = ldv(in, base + i * 256 + tid, dm);
        s += v[i];
        q += v[i] * v[i];
    }
    rs[tid] = s; rq[tid] = q;
    __syncthreads();
    for (int st = 128; st > 0; st >>= 1) {
        if (tid < st) { rs[tid] += rs[tid + st]; rq[tid] += rq[tid + st]; }
        __syncthreads();
    }
    const float mean = rs[0] * (1.0f / 768.0f);
    const float var  = rq[0] * (1.0f / 768.0f) - mean * mean;
    const float rstd = rsqrtf(var + 1e-5f);
#pragma unroll
    for (int i = 0; i < 3; ++i) {
        const int c = i * 256 + tid;
        out[base + c] = (bf16_t)((v[i] - mean) * rstd * ldv(gam, c, pm) + ldv(bet, c, pm));
    }
}

// ---------------------------------------------------------------- MFMA GEMM: C = A * B^T (bf16 out)
#define BM 128
#define BN 128
#define BK 64
#define LDT 72

__global__ __launch_bounds__(256)
void gemm_bt(const bf16_t* __restrict__ A, const bf16_t* __restrict__ B,
             bf16_t* __restrict__ C,
             int K, int lda, int ldb, int ldc,
             const void* __restrict__ bias, const int* __restrict__ flagp,
             const bf16_t* __restrict__ res, int do_relu) {
    __shared__ bf16_t As[BM][LDT];
    __shared__ bf16_t Bs[BN][LDT];
    const int bmode = *flagp;
    const int n0 = blockIdx.x * BN;
    const int m0 = blockIdx.y * BM;
    const bf16_t* Az = A + (long)m0 * lda;
    const bf16_t* Bz = B + (long)n0 * ldb;

    const int tid  = threadIdx.x;
    const int lane = tid & 63;
    const int w    = tid >> 6;
    const int wm   = (w >> 1) * 64;
    const int wn   = (w & 1) * 64;
    const int l15  = lane & 15;
    const int quad = lane >> 4;
    const int srow = tid >> 3;
    const int scol = (tid & 7) * 8;

    const f32x4 fz = {0.f, 0.f, 0.f, 0.f};
    f32x4 acc[4][4];
#pragma unroll
    for (int i = 0; i < 4; ++i)
#pragma unroll
        for (int j = 0; j < 4; ++j) acc[i][j] = fz;

    for (int k0 = 0; k0 < K; k0 += BK) {
        __syncthreads();
#pragma unroll
        for (int p = 0; p < 4; ++p) {
            const int r = srow + p * 32;
            *(bf16x8*)(&As[r][scol]) = *(const bf16x8*)(Az + (long)r * lda + k0 + scol);
            *(bf16x8*)(&Bs[r][scol]) = *(const bf16x8*)(Bz + (long)r * ldb + k0 + scol);
        }
        __syncthreads();
#pragma unroll
        for (int kk = 0; kk < BK; kk += 32) {
            bf16x8 af[4], bfr[4];
#pragma unroll
            for (int i = 0; i < 4; ++i)
                af[i] = *(const bf16x8*)(&As[wm + i * 16 + l15][kk + quad * 8]);
#pragma unroll
            for (int j = 0; j < 4; ++j)
                bfr[j] = *(const bf16x8*)(&Bs[wn + j * 16 + l15][kk + quad * 8]);
#pragma unroll
            for (int i = 0; i < 4; ++i)
#pragma unroll
                for (int j = 0; j < 4; ++j)
                    acc[i][j] = mfma16(af[i], bfr[j], acc[i][j]);
        }
    }

#pragma unroll
    for (int i = 0; i < 4; ++i) {
#pragma unroll
        for (int j = 0; j < 4; ++j) {
            const int mb = m0 + wm + i * 16 + quad * 4;
            const int nc = n0 + wn + j * 16 + l15;
#pragma unroll
            for (int r = 0; r < 4; ++r) {
                float v = acc[i][j][r];
                if (bias) v += ldv(bias, nc, bmode);
                if (do_relu) v = fmaxf(v, 0.0f);
                if (res) v += (float)res[(long)(mb + r) * ldc + nc];
                C[(long)(mb + r) * ldc + nc] = (bf16_t)v;
            }
        }
    }
}

// ---------------------------------------------------------------- MFMA GEMM accumulate: Cf32 (+)= A * B^T
__global__ __launch_bounds__(256)
void gemm_acc(const bf16_t* __restrict__ A, const bf16_t* __restrict__ B,
              float* __restrict__ C,
              int K, int lda, int ldb, int ldc, int first) {
    __shared__ bf16_t As[BM][LDT];
    __shared__ bf16_t Bs[BN][LDT];
    const int n0 = blockIdx.x * BN;
    const int m0 = blockIdx.y * BM;
    const bf16_t* Az = A + (long)m0 * lda;
    const bf16_t* Bz = B + (long)n0 * ldb;

    const int tid  = threadIdx.x;
    const int lane = tid & 63;
    const int w    = tid >> 6;
    const int wm   = (w >> 1) * 64;
    const int wn   = (w & 1) * 64;
    const int l15  = lane & 15;
    const int quad = lane >> 4;
    const int srow = tid >> 3;
    const int scol = (tid & 7) * 8;

    const f32x4 fz = {0.f, 0.f, 0.f, 0.f};
    f32x4 acc[4][4];
#pragma unroll
    for (int i = 0; i < 4; ++i)
#pragma unroll
        for (int j = 0; j < 4; ++j) acc[i][j] = fz;

    for (int k0 = 0; k0 < K; k0 += BK) {
        __syncthreads();
#pragma unroll
        for (int p = 0; p < 4; ++p) {
            const int r = srow + p * 32;
            *(bf16x8*)(&As[r][scol]) = *(const bf16x8*)(Az + (long)r * lda + k0 + scol);
            *(bf16x8*)(&Bs[r][scol]) = *(const bf16x8*)(Bz + (long)r * ldb + k0 + scol);
        }
        __syncthreads();
#pragma unroll
        for (int kk = 0; kk < BK; kk += 32) {
            bf16x8 af[4], bfr[4];
#pragma unroll
            for (int i = 0; i < 4; ++i)
                af[i] = *(const bf16x8*)(&As[wm + i * 16 + l15][kk + quad * 8]);
#pragma unroll
            for (int j = 0; j < 4; ++j)
                bfr[j] = *(const bf16x8*)(&Bs[wn + j * 16 + l15][kk + quad * 8]);
#pragma unroll
            for (int i = 0; i < 4; ++i)
#pragma unroll
                for (int j = 0; j < 4; ++j)
                    acc[i][j] = mfma16(af[i], bfr[j], acc[i][j]);
        }
    }

#pragma unroll
    for (int i = 0; i < 4; ++i) {
#pragma unroll
        for (int j = 0; j < 4; ++j) {
            const int mb = m0 + wm + i * 16 + quad * 4;
            const int nc = n0 + wn + j * 16 + l15;
#pragma unroll
            for (int r = 0; r < 4; ++r) {
                float* cp = C + (long)(mb + r) * ldc + nc;
                float v = acc[i][j][r];
                if (!first) v += *cp;
                *cp = v;
            }
        }
    }
}

// ---------------------------------------------------------------- fused S -> softmax -> P (global)
// Per (b, 16-row n-tile, head hh of 2-head group g):
//   S = Q K^T / 8 (full M=1024 in regs; 8 col-waves), exact softmax,
//   P -> Pl (LDS) -> coalesced bf16 store to Pbuf[z=(b*2+hh)][n][m], ld 1024.
// Grid x = 1024: b = x&7 (XCD co-location), nt = (x>>3)&63, hh = x>>9.
// The P@yn contraction moved to a proper tiled GEMM (gemm_T) — the old fused
// phase-2 was request-latency-bound (16 cache lines per 16B-lane load, 16-row
// n-tile re-reading all of yn per block: MfmaUtil 5.7%, all pipes idle).
__global__ __launch_bounds__(512, 8)
void fused_S(const bf16_t* __restrict__ Q, const bf16_t* __restrict__ Kp,
             bf16_t* __restrict__ P, int g) {
    __shared__ bf16_t Pl[16][1032];
    __shared__ float  rmax[8][16];
    __shared__ float  rsum[8][16];

    const int bx   = blockIdx.x;
    const int b    = bx & 7;
    const int n0   = ((bx >> 3) & 63) * 16;
    const int hh   = bx >> 9;           // head within the 2-head group
    const int h    = g * 2 + hh;        // global head
    const int tid  = threadIdx.x;
    const int w    = tid >> 6;          // 0..7 col-waves
    const int lane = tid & 63;
    const int l15  = lane & 15;
    const int quad = lane >> 4;

    const f32x4 fz = {0.f, 0.f, 0.f, 0.f};
    const long qoff = (long)(b * 1024 + n0 + l15) * 768 + h * 64 + quad * 8;
    const long koff = (long)(b * 1024) * 768 + h * 64 + quad * 8;

    // ---- S = Q K^T: this wave covers cols m = w*128 + f*16 + l15
    f32x4 s[8];
#pragma unroll
    for (int f = 0; f < 8; ++f) s[f] = fz;
    const bf16x8 qa0 = *(const bf16x8*)(Q + qoff);
    const bf16x8 qa1 = *(const bf16x8*)(Q + qoff + 32);
#pragma unroll
    for (int f = 0; f < 8; ++f) {
        const int m = w * 128 + f * 16 + l15;
        const bf16_t* kp = Kp + koff + (long)m * 768;
        s[f] = mfma16(qa0, *(const bf16x8*)kp, s[f]);
        s[f] = mfma16(qa1, *(const bf16x8*)(kp + 32), s[f]);
    }
    // ---- softmax over m; lane owns rows quad*4 + r
    float rm[4] = {-3e38f, -3e38f, -3e38f, -3e38f};
#pragma unroll
    for (int f = 0; f < 8; ++f)
#pragma unroll
        for (int r = 0; r < 4; ++r) {
            s[f][r] *= 0.125f;
            rm[r] = fmaxf(rm[r], s[f][r]);
        }
#pragma unroll
    for (int off = 1; off < 16; off <<= 1)
#pragma unroll
        for (int r = 0; r < 4; ++r) rm[r] = fmaxf(rm[r], __shfl_xor(rm[r], off));
    if (l15 == 0) {
#pragma unroll
        for (int r = 0; r < 4; ++r) rmax[w][quad * 4 + r] = rm[r];
    }
    __syncthreads();
    float gm[4];
#pragma unroll
    for (int r = 0; r < 4; ++r) {
        float mx = rmax[0][quad * 4 + r];
#pragma unroll
        for (int w2 = 1; w2 < 8; ++w2) mx = fmaxf(mx, rmax[w2][quad * 4 + r]);
        gm[r] = mx;
    }
    float ps[4] = {0.f, 0.f, 0.f, 0.f};
#pragma unroll
    for (int f = 0; f < 8; ++f)
#pragma unroll
        for (int r = 0; r < 4; ++r) {
            const float p = __expf(s[f][r] - gm[r]);
            s[f][r] = p;
            ps[r] += p;
        }
#pragma unroll
    for (int off = 1; off < 16; off <<= 1)
#pragma unroll
        for (int r = 0; r < 4; ++r) ps[r] += __shfl_xor(ps[r], off);
    if (l15 == 0) {
#pragma unroll
        for (int r = 0; r < 4; ++r) rsum[w][quad * 4 + r] = ps[r];
    }
    __syncthreads();
#pragma unroll
    for (int r = 0; r < 4; ++r) {
        float ss = 0.f;
#pragma unroll
        for (int w2 = 0; w2 < 8; ++w2) ss += rsum[w2][quad * 4 + r];
        gm[r] = 1.0f / ss;
    }
#pragma unroll
    for (int f = 0; f < 8; ++f)
#pragma unroll
        for (int r = 0; r < 4; ++r)
            Pl[quad * 4 + r][w * 128 + f * 16 + l15] = (bf16_t)(s[f][r] * gm[r]);
    __syncthreads();

    // ---- coalesced store of the 16x1024 P tile (32 threads per row -> 2KB rows)
    const long pbase = ((long)(b * 2 + hh) * 1024 + n0) * 1024;
    const int rr = tid >> 5;
    const int c0 = (tid & 31) * 32;
    bf16_t* dst = P + pbase + (long)rr * 1024 + c0;
#pragma unroll
    for (int u = 0; u < 4; ++u)
        *(bf16x8*)(dst + u * 8) = *(const bf16x8*)(&Pl[rr][c0 + u * 8]);
}

// ---------------------------------------------------------------- batched GEMM: T_z = P_z @ yn_b
// z = b*2+hh (16 batches); A = P_z [1024 n][1024 m]; B = ynT_b [768 e][1024 m];
// C = Tb[(b*1024+n)][hh*768+e], ld 1536. Grid (6, 8, 16).
__global__ __launch_bounds__(256)
void gemm_T(const bf16_t* __restrict__ P, const bf16_t* __restrict__ YNT,
            bf16_t* __restrict__ Tb) {
    __shared__ bf16_t As[BM][LDT];
    __shared__ bf16_t Bs[BN][LDT];
    const int z = blockIdx.z;
    const bf16_t* A = P   + (long)z * (1024 * 1024);
    const bf16_t* B = YNT + (long)(z >> 1) * (768 * 1024);
    bf16_t*       C = Tb  + (long)(z >> 1) * (1024 * 1536) + (z & 1) * 768;
    const int n0 = blockIdx.x * BN;
    const int m0 = blockIdx.y * BM;
    const bf16_t* Az = A + (long)m0 * 1024;
    const bf16_t* Bz = B + (long)n0 * 1024;

    const int tid  = threadIdx.x;
    const int lane = tid & 63;
    const int w    = tid >> 6;
    const int wm   = (w >> 1) * 64;
    const int wn   = (w & 1) * 64;
    const int l15  = lane & 15;
    const int quad = lane >> 4;
    const int srow = tid >> 3;
    const int scol = (tid & 7) * 8;

    const f32x4 fz = {0.f, 0.f, 0.f, 0.f};
    f32x4 acc[4][4];
#pragma unroll
    for (int i = 0; i < 4; ++i)
#pragma unroll
        for (int j = 0; j < 4; ++j) acc[i][j] = fz;

    for (int k0 = 0; k0 < 1024; k0 += BK) {
        __syncthreads();
#pragma unroll
        for (int p = 0; p < 4; ++p) {
            const int r = srow + p * 32;
            *(bf16x8*)(&As[r][scol]) = *(const bf16x8*)(Az + (long)r * 1024 + k0 + scol);
            *(bf16x8*)(&Bs[r][scol]) = *(const bf16x8*)(Bz + (long)r * 1024 + k0 + scol);
        }
        __syncthreads();
#pragma unroll
        for (int kk = 0; kk < BK; kk += 32) {
            bf16x8 af[4], bfr[4];
#pragma unroll
            for (int i = 0; i < 4; ++i)
                af[i] = *(const bf16x8*)(&As[wm + i * 16 + l15][kk + quad * 8]);
#pragma unroll
            for (int j = 0; j < 4; ++j)
                bfr[j] = *(const bf16x8*)(&Bs[wn + j * 16 + l15][kk + quad * 8]);
#pragma unroll
            for (int i = 0; i < 4; ++i)
#pragma unroll
                for (int j = 0; j < 4; ++j)
                    acc[i][j] = mfma16(af[i], bfr[j], acc[i][j]);
        }
    }

#pragma unroll
    for (int i = 0; i < 4; ++i) {
#pragma unroll
        for (int j = 0; j < 4; ++j) {
            const int mb = m0 + wm + i * 16 + quad * 4;
            const int nc = n0 + wn + j * 16 + l15;
#pragma unroll
            for (int r = 0; r < 4; ++r)
                C[(long)(mb + r) * 1536 + nc] = (bf16_t)acc[i][j][r];
        }
    }
}

// ---------------------------------------------------------------- h_pre epilogue
__global__ __launch_bounds__(256)
void hpre_ep(const float* __restrict__ dx, const float* __restrict__ bvs,
             const bf16_t* __restrict__ xn, bf16_t* __restrict__ hp) {
    const long i = (long)blockIdx.x * 256 + threadIdx.x;   // grid covers 6291456
    const int e = (int)(i % 768);
    hp[i] = (bf16_t)(dx[i] + bvs[e] + (float)xn[i]);
}

// ---------------------------------------------------------------- output emit
__global__ __launch_bounds__(256)
void emit2(const bf16_t* __restrict__ a, const bf16_t* __restrict__ b,
           void* __restrict__ out, const int* __restrict__ flagp) {
    const int mode = *flagp;
    const long n = 6291456;
    const long stride = (long)gridDim.x * blockDim.x;
    for (long i = (long)blockIdx.x * blockDim.x + threadIdx.x; i < 2 * n; i += stride) {
        const bf16_t v = (i < n) ? a[i] : b[i - n];
        if (mode) ((float*)out)[i] = (float)v;
        else      ((bf16_t*)out)[i] = v;
    }
}

// ---------------------------------------------------------------- launch
extern "C" void kernel_launch(void* const* d_in, const int* in_sizes, int n_in,
                              void* d_out, int out_size, void* d_ws, size_t ws_size,
                              hipStream_t stream) {
    (void)in_sizes; (void)n_in; (void)out_size; (void)ws_size;

    const void* x    = d_in[0];
    const void* y    = d_in[1];
    const void* ln1g = d_in[2];
    const void* ln1b = d_in[3];
    const void* ln2g = d_in[4];
    const void* ln2b = d_in[5];
    const void* ln3g = d_in[6];
    const void* ln3b = d_in[7];
    const void* wq   = d_in[8];
    const void* bq   = d_in[9];
    const void* wk   = d_in[10];
    const void* bk   = d_in[11];
    const void* wv   = d_in[12];
    const void* bv   = d_in[13];
    const void* wi   = d_in[14];
    const void* bi   = d_in[15];
    const void* wo   = d_in[16];
    const void* bo   = d_in[17];

    // workspace layout (canonical bf16 unless noted), ~165.7 MB
    char* ws = (char*)d_ws;
    bf16_t* xn    = (bf16_t*)(ws + 0);           // 12,582,912
    bf16_t* ynb   = (bf16_t*)(ws + 12582912);    // 12,582,912 (output 1, kept till emit)
    bf16_t* ynT   = (bf16_t*)(ws + 25165824);    // 12,582,912
    bf16_t* qb    = (bf16_t*)(ws + 37748736);    // 12,582,912 (Q; later h_pre)
    bf16_t* kb    = (bf16_t*)(ws + 50331648);    // 12,582,912 (K; later hn)
    bf16_t* Tb2   = (bf16_t*)(ws + 62914560);    // 8192 x 1536 = 25,165,824 (later mid)
    float*  dxf   = (float*) (ws + 88080384);    // 8192 x 768 x 4 = 25,165,824
    bf16_t* W2T   = (bf16_t*)(ws + 113246208);   // 768 x 9216 = 14,155,776
    bf16_t* Pbuf  = (bf16_t*)(ws + 127401984);   // 16 x 1024 x 1024 = 33,554,432
    bf16_t* wqT   = (bf16_t*)(ws + 160956416);   // 1,179,648
    bf16_t* wkT   = (bf16_t*)(ws + 162136064);
    bf16_t* wiT   = (bf16_t*)(ws + 163315712);
    bf16_t* woT   = (bf16_t*)(ws + 164495360);
    float*  bvs   = (float*) (ws + 165675008);   // 3,072
    int*    flag  = (int*)   (ws + 165678080);   // flag[0]=fp32 mode, flag[1]=0
    bf16_t* hpre  = qb;
    bf16_t* hn    = kb;
    bf16_t* mid   = Tb2;
    bf16_t* res0  = xn;
    const int* F  = flag;
    const int* Z  = flag + 1;

    detect_dtype<<<1, 256, 0, stream>>>(x, flag);

    const dim3 tb(32, 8);
    transpose_cvt<<<dim3(24, 24, 1), tb, 0, stream>>>(wq, wqT, 768, 768, F);
    transpose_cvt<<<dim3(24, 24, 1), tb, 0, stream>>>(wk, wkT, 768, 768, F);
    transpose_cvt<<<dim3(24, 24, 1), tb, 0, stream>>>(wi, wiT, 768, 768, F);
    transpose_cvt<<<dim3(24, 24, 1), tb, 0, stream>>>(wo, woT, 768, 768, F);
    transpose_wv<<<dim3(24, 24, 12), tb, 0, stream>>>(wv, W2T, F);
    bvsum_k<<<3, 256, 0, stream>>>(bv, bvs, F);

    ln768<<<8192, 256, 0, stream>>>(x, xn, ln1g, ln1b, F, F);
    ln768<<<8192, 256, 0, stream>>>(y, ynb, ln2g, ln2b, F, F);
    transpose_cvt<<<dim3(24, 32, 8), tb, 0, stream>>>(ynb, ynT, 1024, 768, Z);

    // Q = xn @ wq + bq; K = yn @ wk + bk
    gemm_bt<<<dim3(6, 64), 256, 0, stream>>>(xn, wqT, qb, 768, 768, 768, 768,
                                             bq, F, nullptr, 0);
    gemm_bt<<<dim3(6, 64), 256, 0, stream>>>(ynb, wkT, kb, 768, 768, 768, 768,
                                             bk, F, nullptr, 0);

    // attention in 6 head-groups of 2:
    //   P = softmax(QK^T/8)  (materialized, 33.5 MB)
    //   T = P @ yn           (batched 128x128-tile MFMA GEMM, K=1024)
    //   dx (+)= T @ W2^T     (K=1536 slice of W2T)
    for (int g = 0; g < 6; ++g) {
        fused_S<<<1024, 512, 0, stream>>>(qb, kb, Pbuf, g);
        gemm_T<<<dim3(6, 8, 16), 256, 0, stream>>>(Pbuf, ynT, Tb2);
        gemm_acc<<<dim3(6, 64), 256, 0, stream>>>(Tb2, W2T + g * 1536, dxf,
                                                  1536, 1536, 9216, 768, g == 0);
    }

    // h_pre = xn + dx + sum_h bv_h   (qb dead -> reuse)
    hpre_ep<<<24576, 256, 0, stream>>>(dxf, bvs, xn, hpre);

    ln768<<<8192, 256, 0, stream>>>(hpre, hn, ln3g, ln3b, Z, F);

    gemm_bt<<<dim3(6, 64), 256, 0, stream>>>(hn, wiT, mid, 768, 768, 768, 768,
                                             bi, F, nullptr, 1);
    gemm_bt<<<dim3(6, 64), 256, 0, stream>>>(mid, woT, res0, 768, 768, 768, 768,
                                             bo, F, hn, 0);

    emit2<<<2048, 256, 0, stream>>>(res0, ynb, d_out, F);
}

// Round 2
// 1065.518 us; speedup vs baseline: 1.6574x; 1.0577x over previous
//
#include <hip/hip_runtime.h>
#include <hip/hip_bf16.h>
#include <stdint.h>

// Inputs may be float32 OR bf16 (detected at runtime on-device); internal
// canonical dtype is bf16; compute in fp32; output emitted in detected dtype.
typedef __bf16 bf16_t;
typedef __bf16 bf16x8 __attribute__((ext_vector_type(8)));
typedef float  f32x4  __attribute__((ext_vector_type(4)));

typedef __attribute__((address_space(3))) unsigned int lds_u32;
typedef const __attribute__((address_space(1))) unsigned int glob_u32;
#define GLDS16(g, l) __builtin_amdgcn_global_load_lds((glob_u32*)(g), (lds_u32*)(l), 16, 0, 0)

__device__ __forceinline__ f32x4 mfma16(bf16x8 a, bf16x8 b, f32x4 c) {
    // D[row=quad*4+r][col=lane&15]; A[row=lane&15][k=quad*8+j]; B[k=quad*8+j][col=lane&15]
    return __builtin_amdgcn_mfma_f32_16x16x32_bf16(a, b, c, 0, 0, 0);
}

__device__ __forceinline__ float ldv(const void* p, long i, int fp32mode) {
    return fp32mode ? ((const float*)p)[i] : (float)((const bf16_t*)p)[i];
}

// ---------------------------------------------------------------- dtype detect
__global__ __launch_bounds__(256)
void detect_dtype(const void* __restrict__ x, int* __restrict__ flag) {
    __shared__ int cnt;
    if (threadIdx.x == 0) cnt = 0;
    __syncthreads();
    const bf16_t* p = (const bf16_t*)x;
    int local = 0;
    for (int i = threadIdx.x; i < 4096; i += 256) {
        const float v = (float)p[i];
        if (!(fabsf(v) < 1e6f)) local++;   // catches NaN too
    }
    atomicAdd(&cnt, local);
    __syncthreads();
    if (threadIdx.x == 0) { flag[0] = (cnt >= 16) ? 1 : 0; flag[1] = 0; }
}

// ---------------------------------------------------------------- convert-transpose (batched)
__global__ __launch_bounds__(256)
void transpose_cvt(const void* __restrict__ in, bf16_t* __restrict__ out,
                   int R, int C, const int* __restrict__ flagp) {
    __shared__ bf16_t t[32][33];
    const int mode = *flagp;
    const long zi = (long)blockIdx.z * R * C;
    const int c0 = blockIdx.x * 32;
    const int r0 = blockIdx.y * 32;
    const int x  = threadIdx.x;
    const int y0 = threadIdx.y;
    for (int yy = y0; yy < 32; yy += 8)
        t[yy][x] = (bf16_t)ldv(in, zi + (long)(r0 + yy) * C + c0 + x, mode);
    __syncthreads();
    for (int yy = y0; yy < 32; yy += 8)
        out[zi + (long)(c0 + yy) * R + r0 + x] = t[x][yy];
}

// ---------------------------------------------------------------- wv permuted transpose
// W2T[e][h*768+k] = wv[k][h*768+e]   (both ld 9216)
__global__ __launch_bounds__(256)
void transpose_wv(const void* __restrict__ in, bf16_t* __restrict__ out,
                  const int* __restrict__ flagp) {
    __shared__ bf16_t t[32][33];
    const int mode = *flagp;
    const int h  = blockIdx.z;
    const int e0 = blockIdx.x * 32;
    const int k0 = blockIdx.y * 32;
    const int x  = threadIdx.x;
    const int y0 = threadIdx.y;
    for (int yy = y0; yy < 32; yy += 8)
        t[yy][x] = (bf16_t)ldv(in, (long)(k0 + yy) * 9216 + h * 768 + e0 + x, mode);
    __syncthreads();
    for (int yy = y0; yy < 32; yy += 8)
        out[(long)(e0 + yy) * 9216 + h * 768 + k0 + x] = t[x][yy];
}

// ---------------------------------------------------------------- bv head-sum
__global__ __launch_bounds__(256)
void bvsum_k(const void* __restrict__ bv, float* __restrict__ out,
             const int* __restrict__ flagp) {
    const int mode = *flagp;
    const int e = blockIdx.x * 256 + threadIdx.x;
    if (e < 768) {
        float s = 0.f;
#pragma unroll
        for (int h = 0; h < 12; ++h) s += ldv(bv, h * 768 + e, mode);
        out[e] = s;
    }
}

// ---------------------------------------------------------------- layernorm (768 cols)
__global__ __launch_bounds__(256)
void ln768(const void* __restrict__ in, bf16_t* __restrict__ out,
           const void* __restrict__ gam, const void* __restrict__ bet,
           const int* __restrict__ dmodep, const int* __restrict__ pmodep) {
    __shared__ float rs[256], rq[256];
    const int dm = *dmodep, pm = *pmodep;
    const long base = (long)blockIdx.x * 768;
    const int tid = threadIdx.x;
    float v[3];
    float s = 0.f, q = 0.f;
#pragma unroll
    for (int i = 0; i < 3; ++i) {
        v[i] = ldv(in, base + i * 256 + tid, dm);
        s += v[i];
        q += v[i] * v[i];
    }
    rs[tid] = s; rq[tid] = q;
    __syncthreads();
    for (int st = 128; st > 0; st >>= 1) {
        if (tid < st) { rs[tid] += rs[tid + st]; rq[tid] += rq[tid + st]; }
        __syncthreads();
    }
    const float mean = rs[0] * (1.0f / 768.0f);
    const float var  = rq[0] * (1.0f / 768.0f) - mean * mean;
    const float rstd = rsqrtf(var + 1e-5f);
#pragma unroll
    for (int i = 0; i < 3; ++i) {
        const int c = i * 256 + tid;
        out[base + c] = (bf16_t)((v[i] - mean) * rstd * ldv(gam, c, pm) + ldv(bet, c, pm));
    }
}

// ================================================================ GEMM common
// 128x128 tile, BK=64, linear LDS [128][64] staged via global_load_lds width-16
// with both-sides XOR swizzle (byte ^= (row&7)<<4): conflict-free ds_read_b128.
// 2-phase double-buffered pipeline: stage(t+1) issued before MFMA(t), one
// barrier per K-step -> loads in flight across the compute block (latency fix
// for the 1.5-3 block/CU grids of this problem).
#define BM 128
#define BN 128
#define BK 64
#define TILEB 16384   // bytes per [128][64] bf16 tile

__device__ __forceinline__ void stage_ab(const bf16_t* Az, const bf16_t* Bz,
                                         int lda, int ldb, int k0,
                                         char* lA, char* lB, int tid) {
    const int srow = tid >> 3;
    const int cb   = (tid & 7) * 16;
#pragma unroll
    for (int p = 0; p < 4; ++p) {
        const int row = srow + p * 32;
        const int sc  = cb ^ ((row & 7) << 4);
        GLDS16((const char*)(Az + (long)row * lda + k0) + sc, lA + p * 4096);
        GLDS16((const char*)(Bz + (long)row * ldb + k0) + sc, lB + p * 4096);
    }
}

__device__ __forceinline__ void compute_tile(const char* As, const char* Bs,
                                             int wm, int wn, int l15, int quad,
                                             f32x4 acc[4][4]) {
#pragma unroll
    for (int kk = 0; kk < BK; kk += 32) {
        bf16x8 af[4], bfr[4];
        const int cb = kk * 2 + quad * 16;
#pragma unroll
        for (int i = 0; i < 4; ++i) {
            const int r = wm + i * 16 + l15;
            af[i] = *(const bf16x8*)(As + r * 128 + (cb ^ ((r & 7) << 4)));
        }
#pragma unroll
        for (int j = 0; j < 4; ++j) {
            const int r = wn + j * 16 + l15;
            bfr[j] = *(const bf16x8*)(Bs + r * 128 + (cb ^ ((r & 7) << 4)));
        }
#pragma unroll
        for (int i = 0; i < 4; ++i)
#pragma unroll
            for (int j = 0; j < 4; ++j)
                acc[i][j] = mfma16(af[i], bfr[j], acc[i][j]);
    }
}

__device__ __forceinline__ void kloop(const bf16_t* Az, const bf16_t* Bz,
                                      int K, int lda, int ldb, int tid,
                                      char* AsB, char* BsB,
                                      int wm, int wn, int l15, int quad,
                                      f32x4 acc[4][4]) {
    char* lA = AsB + (tid >> 6) * 1024;   // wave-uniform
    char* lB = BsB + (tid >> 6) * 1024;
    int cur = 0;
    stage_ab(Az, Bz, lda, ldb, 0, lA, lB, tid);
    __syncthreads();
    const int NT = K >> 6;
    for (int t = 0; t < NT - 1; ++t) {
        const int nb = cur ^ 1;
        stage_ab(Az, Bz, lda, ldb, (t + 1) << 6, lA + nb * TILEB, lB + nb * TILEB, tid);
        compute_tile(AsB + cur * TILEB, BsB + cur * TILEB, wm, wn, l15, quad, acc);
        __syncthreads();
        cur = nb;
    }
    compute_tile(AsB + cur * TILEB, BsB + cur * TILEB, wm, wn, l15, quad, acc);
}

// bijective XCD chunk swizzle over nwg blocks (nwg % 8 == 0)
__device__ __forceinline__ int xcd_swz(int lin, int nwg) {
    return (lin & 7) * (nwg >> 3) + (lin >> 3);
}

// ---------------------------------------------------------------- MFMA GEMM: C = A * B^T (bf16 out)
__global__ __launch_bounds__(256, 2)
void gemm_bt(const bf16_t* __restrict__ A, const bf16_t* __restrict__ B,
             bf16_t* __restrict__ C,
             int K, int lda, int ldb, int ldc,
             const void* __restrict__ bias, const int* __restrict__ flagp,
             const bf16_t* __restrict__ res, int do_relu) {
    __shared__ bf16_t As[2][BM][BK];
    __shared__ bf16_t Bs[2][BN][BK];
    const int bmode = *flagp;
    const int swz = xcd_swz(blockIdx.y * gridDim.x + blockIdx.x, gridDim.x * gridDim.y);
    const int n0 = (swz % gridDim.x) * BN;
    const int m0 = (swz / gridDim.x) * BM;
    const bf16_t* Az = A + (long)m0 * lda;
    const bf16_t* Bz = B + (long)n0 * ldb;

    const int tid  = threadIdx.x;
    const int lane = tid & 63;
    const int w    = tid >> 6;
    const int wm   = (w >> 1) * 64;
    const int wn   = (w & 1) * 64;
    const int l15  = lane & 15;
    const int quad = lane >> 4;

    const f32x4 fz = {0.f, 0.f, 0.f, 0.f};
    f32x4 acc[4][4];
#pragma unroll
    for (int i = 0; i < 4; ++i)
#pragma unroll
        for (int j = 0; j < 4; ++j) acc[i][j] = fz;

    kloop(Az, Bz, K, lda, ldb, tid, (char*)As, (char*)Bs, wm, wn, l15, quad, acc);

#pragma unroll
    for (int i = 0; i < 4; ++i) {
#pragma unroll
        for (int j = 0; j < 4; ++j) {
            const int mb = m0 + wm + i * 16 + quad * 4;
            const int nc = n0 + wn + j * 16 + l15;
#pragma unroll
            for (int r = 0; r < 4; ++r) {
                float v = acc[i][j][r];
                if (bias) v += ldv(bias, nc, bmode);
                if (do_relu) v = fmaxf(v, 0.0f);
                if (res) v += (float)res[(long)(mb + r) * ldc + nc];
                C[(long)(mb + r) * ldc + nc] = (bf16_t)v;
            }
        }
    }
}

// ---------------------------------------------------------------- merged Q/K projection
__global__ __launch_bounds__(256, 2)
void gemm_qk(const bf16_t* __restrict__ xn, const bf16_t* __restrict__ ynb,
             const bf16_t* __restrict__ wqT, const bf16_t* __restrict__ wkT,
             bf16_t* __restrict__ qb, bf16_t* __restrict__ kb,
             const void* __restrict__ bq, const void* __restrict__ bk,
             const int* __restrict__ flagp) {
    __shared__ bf16_t As[2][BM][BK];
    __shared__ bf16_t Bs[2][BN][BK];
    const int bmode = *flagp;
    const int z = blockIdx.z;
    const bf16_t* A = z ? ynb : xn;
    const bf16_t* B = z ? wkT : wqT;
    bf16_t*       C = z ? kb  : qb;
    const void* bias = z ? bk : bq;
    const int swz = xcd_swz(blockIdx.y * gridDim.x + blockIdx.x, gridDim.x * gridDim.y);
    const int n0 = (swz % gridDim.x) * BN;
    const int m0 = (swz / gridDim.x) * BM;
    const bf16_t* Az = A + (long)m0 * 768;
    const bf16_t* Bz = B + (long)n0 * 768;

    const int tid  = threadIdx.x;
    const int lane = tid & 63;
    const int w    = tid >> 6;
    const int wm   = (w >> 1) * 64;
    const int wn   = (w & 1) * 64;
    const int l15  = lane & 15;
    const int quad = lane >> 4;

    const f32x4 fz = {0.f, 0.f, 0.f, 0.f};
    f32x4 acc[4][4];
#pragma unroll
    for (int i = 0; i < 4; ++i)
#pragma unroll
        for (int j = 0; j < 4; ++j) acc[i][j] = fz;

    kloop(Az, Bz, 768, 768, 768, tid, (char*)As, (char*)Bs, wm, wn, l15, quad, acc);

#pragma unroll
    for (int i = 0; i < 4; ++i) {
#pragma unroll
        for (int j = 0; j < 4; ++j) {
            const int mb = m0 + wm + i * 16 + quad * 4;
            const int nc = n0 + wn + j * 16 + l15;
#pragma unroll
            for (int r = 0; r < 4; ++r)
                C[(long)(mb + r) * 768 + nc] = (bf16_t)(acc[i][j][r] + ldv(bias, nc, bmode));
        }
    }
}

// ---------------------------------------------------------------- MFMA GEMM accumulate: Cf32 (+)= A * B^T
__global__ __launch_bounds__(256, 2)
void gemm_acc(const bf16_t* __restrict__ A, const bf16_t* __restrict__ B,
              float* __restrict__ C,
              int K, int lda, int ldb, int ldc, int first) {
    __shared__ bf16_t As[2][BM][BK];
    __shared__ bf16_t Bs[2][BN][BK];
    const int swz = xcd_swz(blockIdx.y * gridDim.x + blockIdx.x, gridDim.x * gridDim.y);
    const int n0 = (swz % gridDim.x) * BN;
    const int m0 = (swz / gridDim.x) * BM;
    const bf16_t* Az = A + (long)m0 * lda;
    const bf16_t* Bz = B + (long)n0 * ldb;

    const int tid  = threadIdx.x;
    const int lane = tid & 63;
    const int w    = tid >> 6;
    const int wm   = (w >> 1) * 64;
    const int wn   = (w & 1) * 64;
    const int l15  = lane & 15;
    const int quad = lane >> 4;

    const f32x4 fz = {0.f, 0.f, 0.f, 0.f};
    f32x4 acc[4][4];
#pragma unroll
    for (int i = 0; i < 4; ++i)
#pragma unroll
        for (int j = 0; j < 4; ++j) acc[i][j] = fz;

    kloop(Az, Bz, K, lda, ldb, tid, (char*)As, (char*)Bs, wm, wn, l15, quad, acc);

#pragma unroll
    for (int i = 0; i < 4; ++i) {
#pragma unroll
        for (int j = 0; j < 4; ++j) {
            const int mb = m0 + wm + i * 16 + quad * 4;
            const int nc = n0 + wn + j * 16 + l15;
#pragma unroll
            for (int r = 0; r < 4; ++r) {
                float* cp = C + (long)(mb + r) * ldc + nc;
                float v = acc[i][j][r];
                if (!first) v += *cp;
                *cp = v;
            }
        }
    }
}

// ---------------------------------------------------------------- batched GEMM: T_z = P_z @ yn_b
// z = b*2+hh (16 batches); A = P_z [1024 n][1024 m]; B = ynT_b [768 e][1024 m];
// C = Tb[(b*1024+n)][hh*768+e], ld 1536. Grid (6, 8, 16).
__global__ __launch_bounds__(256, 2)
void gemm_T(const bf16_t* __restrict__ P, const bf16_t* __restrict__ YNT,
            bf16_t* __restrict__ Tb) {
    __shared__ bf16_t As[2][BM][BK];
    __shared__ bf16_t Bs[2][BN][BK];
    const int z = blockIdx.z;
    const bf16_t* A = P   + (long)z * (1024 * 1024);
    const bf16_t* B = YNT + (long)(z >> 1) * (768 * 1024);
    bf16_t*       C = Tb  + (long)(z >> 1) * (1024 * 1536) + (z & 1) * 768;
    const int swz = xcd_swz(blockIdx.y * gridDim.x + blockIdx.x, gridDim.x * gridDim.y);
    const int n0 = (swz % gridDim.x) * BN;
    const int m0 = (swz / gridDim.x) * BM;
    const bf16_t* Az = A + (long)m0 * 1024;
    const bf16_t* Bz = B + (long)n0 * 1024;

    const int tid  = threadIdx.x;
    const int lane = tid & 63;
    const int w    = tid >> 6;
    const int wm   = (w >> 1) * 64;
    const int wn   = (w & 1) * 64;
    const int l15  = lane & 15;
    const int quad = lane >> 4;

    const f32x4 fz = {0.f, 0.f, 0.f, 0.f};
    f32x4 acc[4][4];
#pragma unroll
    for (int i = 0; i < 4; ++i)
#pragma unroll
        for (int j = 0; j < 4; ++j) acc[i][j] = fz;

    kloop(Az, Bz, 1024, 1024, 1024, tid, (char*)As, (char*)Bs, wm, wn, l15, quad, acc);

#pragma unroll
    for (int i = 0; i < 4; ++i) {
#pragma unroll
        for (int j = 0; j < 4; ++j) {
            const int mb = m0 + wm + i * 16 + quad * 4;
            const int nc = n0 + wn + j * 16 + l15;
#pragma unroll
            for (int r = 0; r < 4; ++r)
                C[(long)(mb + r) * 1536 + nc] = (bf16_t)acc[i][j][r];
        }
    }
}

// ---------------------------------------------------------------- fused S -> softmax -> P (global)
// Per (b, 16-row n-tile, head hh of 2-head group g):
//   S = Q K^T / 8 (full M=1024 in regs; 8 col-waves), exact softmax,
//   P -> Pl (LDS) -> coalesced bf16 store to Pbuf[z=(b*2+hh)][n][m], ld 1024.
__global__ __launch_bounds__(512, 8)
void fused_S(const bf16_t* __restrict__ Q, const bf16_t* __restrict__ Kp,
             bf16_t* __restrict__ P, int g) {
    __shared__ bf16_t Pl[16][1032];
    __shared__ float  rmax[8][16];
    __shared__ float  rsum[8][16];

    const int bx   = blockIdx.x;
    const int b    = bx & 7;
    const int n0   = ((bx >> 3) & 63) * 16;
    const int hh   = bx >> 9;           // head within the 2-head group
    const int h    = g * 2 + hh;        // global head
    const int tid  = threadIdx.x;
    const int w    = tid >> 6;          // 0..7 col-waves
    const int lane = tid & 63;
    const int l15  = lane & 15;
    const int quad = lane >> 4;

    const f32x4 fz = {0.f, 0.f, 0.f, 0.f};
    const long qoff = (long)(b * 1024 + n0 + l15) * 768 + h * 64 + quad * 8;
    const long koff = (long)(b * 1024) * 768 + h * 64 + quad * 8;

    // ---- S = Q K^T: this wave covers cols m = w*128 + f*16 + l15
    f32x4 s[8];
#pragma unroll
    for (int f = 0; f < 8; ++f) s[f] = fz;
    const bf16x8 qa0 = *(const bf16x8*)(Q + qoff);
    const bf16x8 qa1 = *(const bf16x8*)(Q + qoff + 32);
#pragma unroll
    for (int f = 0; f < 8; ++f) {
        const int m = w * 128 + f * 16 + l15;
        const bf16_t* kp = Kp + koff + (long)m * 768;
        s[f] = mfma16(qa0, *(const bf16x8*)kp, s[f]);
        s[f] = mfma16(qa1, *(const bf16x8*)(kp + 32), s[f]);
    }
    // ---- softmax over m; lane owns rows quad*4 + r
    float rm[4] = {-3e38f, -3e38f, -3e38f, -3e38f};
#pragma unroll
    for (int f = 0; f < 8; ++f)
#pragma unroll
        for (int r = 0; r < 4; ++r) {
            s[f][r] *= 0.125f;
            rm[r] = fmaxf(rm[r], s[f][r]);
        }
#pragma unroll
    for (int off = 1; off < 16; off <<= 1)
#pragma unroll
        for (int r = 0; r < 4; ++r) rm[r] = fmaxf(rm[r], __shfl_xor(rm[r], off));
    if (l15 == 0) {
#pragma unroll
        for (int r = 0; r < 4; ++r) rmax[w][quad * 4 + r] = rm[r];
    }
    __syncthreads();
    float gm[4];
#pragma unroll
    for (int r = 0; r < 4; ++r) {
        float mx = rmax[0][quad * 4 + r];
#pragma unroll
        for (int w2 = 1; w2 < 8; ++w2) mx = fmaxf(mx, rmax[w2][quad * 4 + r]);
        gm[r] = mx;
    }
    float ps[4] = {0.f, 0.f, 0.f, 0.f};
#pragma unroll
    for (int f = 0; f < 8; ++f)
#pragma unroll
        for (int r = 0; r < 4; ++r) {
            const float p = __expf(s[f][r] - gm[r]);
            s[f][r] = p;
            ps[r] += p;
        }
#pragma unroll
    for (int off = 1; off < 16; off <<= 1)
#pragma unroll
        for (int r = 0; r < 4; ++r) ps[r] += __shfl_xor(ps[r], off);
    if (l15 == 0) {
#pragma unroll
        for (int r = 0; r < 4; ++r) rsum[w][quad * 4 + r] = ps[r];
    }
    __syncthreads();
#pragma unroll
    for (int r = 0; r < 4; ++r) {
        float ss = 0.f;
#pragma unroll
        for (int w2 = 0; w2 < 8; ++w2) ss += rsum[w2][quad * 4 + r];
        gm[r] = 1.0f / ss;
    }
#pragma unroll
    for (int f = 0; f < 8; ++f)
#pragma unroll
        for (int r = 0; r < 4; ++r)
            Pl[quad * 4 + r][w * 128 + f * 16 + l15] = (bf16_t)(s[f][r] * gm[r]);
    __syncthreads();

    // ---- coalesced store of the 16x1024 P tile (32 threads per row -> 2KB rows)
    const long pbase = ((long)(b * 2 + hh) * 1024 + n0) * 1024;
    const int rr = tid >> 5;
    const int c0 = (tid & 31) * 32;
    bf16_t* dst = P + pbase + (long)rr * 1024 + c0;
#pragma unroll
    for (int u = 0; u < 4; ++u)
        *(bf16x8*)(dst + u * 8) = *(const bf16x8*)(&Pl[rr][c0 + u * 8]);
}

// ---------------------------------------------------------------- h_pre epilogue
__global__ __launch_bounds__(256)
void hpre_ep(const float* __restrict__ dx, const float* __restrict__ bvs,
             const bf16_t* __restrict__ xn, bf16_t* __restrict__ hp) {
    const long i = (long)blockIdx.x * 256 + threadIdx.x;   // grid covers 6291456
    const int e = (int)(i % 768);
    hp[i] = (bf16_t)(dx[i] + bvs[e] + (float)xn[i]);
}

// ---------------------------------------------------------------- output emit
__global__ __launch_bounds__(256)
void emit2(const bf16_t* __restrict__ a, const bf16_t* __restrict__ b,
           void* __restrict__ out, const int* __restrict__ flagp) {
    const int mode = *flagp;
    const long n = 6291456;
    const long stride = (long)gridDim.x * blockDim.x;
    for (long i = (long)blockIdx.x * blockDim.x + threadIdx.x; i < 2 * n; i += stride) {
        const bf16_t v = (i < n) ? a[i] : b[i - n];
        if (mode) ((float*)out)[i] = (float)v;
        else      ((bf16_t*)out)[i] = v;
    }
}

// ---------------------------------------------------------------- launch
extern "C" void kernel_launch(void* const* d_in, const int* in_sizes, int n_in,
                              void* d_out, int out_size, void* d_ws, size_t ws_size,
                              hipStream_t stream) {
    (void)in_sizes; (void)n_in; (void)out_size; (void)ws_size;

    const void* x    = d_in[0];
    const void* y    = d_in[1];
    const void* ln1g = d_in[2];
    const void* ln1b = d_in[3];
    const void* ln2g = d_in[4];
    const void* ln2b = d_in[5];
    const void* ln3g = d_in[6];
    const void* ln3b = d_in[7];
    const void* wq   = d_in[8];
    const void* bq   = d_in[9];
    const void* wk   = d_in[10];
    const void* bk   = d_in[11];
    const void* wv   = d_in[12];
    const void* bv   = d_in[13];
    const void* wi   = d_in[14];
    const void* bi   = d_in[15];
    const void* wo   = d_in[16];
    const void* bo   = d_in[17];

    // workspace layout (canonical bf16 unless noted), ~165.7 MB
    char* ws = (char*)d_ws;
    bf16_t* xn    = (bf16_t*)(ws + 0);           // 12,582,912
    bf16_t* ynb   = (bf16_t*)(ws + 12582912);    // 12,582,912 (output 1, kept till emit)
    bf16_t* ynT   = (bf16_t*)(ws + 25165824);    // 12,582,912
    bf16_t* qb    = (bf16_t*)(ws + 37748736);    // 12,582,912 (Q; later h_pre)
    bf16_t* kb    = (bf16_t*)(ws + 50331648);    // 12,582,912 (K; later hn)
    bf16_t* Tb2   = (bf16_t*)(ws + 62914560);    // 8192 x 1536 = 25,165,824 (later mid)
    float*  dxf   = (float*) (ws + 88080384);    // 8192 x 768 x 4 = 25,165,824
    bf16_t* W2T   = (bf16_t*)(ws + 113246208);   // 768 x 9216 = 14,155,776
    bf16_t* Pbuf  = (bf16_t*)(ws + 127401984);   // 16 x 1024 x 1024 = 33,554,432
    bf16_t* wqT   = (bf16_t*)(ws + 160956416);   // 1,179,648
    bf16_t* wkT   = (bf16_t*)(ws + 162136064);
    bf16_t* wiT   = (bf16_t*)(ws + 163315712);
    bf16_t* woT   = (bf16_t*)(ws + 164495360);
    float*  bvs   = (float*) (ws + 165675008);   // 3,072
    int*    flag  = (int*)   (ws + 165678080);   // flag[0]=fp32 mode, flag[1]=0
    bf16_t* hpre  = qb;
    bf16_t* hn    = kb;
    bf16_t* mid   = Tb2;
    bf16_t* res0  = xn;
    const int* F  = flag;
    const int* Z  = flag + 1;

    detect_dtype<<<1, 256, 0, stream>>>(x, flag);

    const dim3 tb(32, 8);
    transpose_cvt<<<dim3(24, 24, 1), tb, 0, stream>>>(wq, wqT, 768, 768, F);
    transpose_cvt<<<dim3(24, 24, 1), tb, 0, stream>>>(wk, wkT, 768, 768, F);
    transpose_cvt<<<dim3(24, 24, 1), tb, 0, stream>>>(wi, wiT, 768, 768, F);
    transpose_cvt<<<dim3(24, 24, 1), tb, 0, stream>>>(wo, woT, 768, 768, F);
    transpose_wv<<<dim3(24, 24, 12), tb, 0, stream>>>(wv, W2T, F);
    bvsum_k<<<3, 256, 0, stream>>>(bv, bvs, F);

    ln768<<<8192, 256, 0, stream>>>(x, xn, ln1g, ln1b, F, F);
    ln768<<<8192, 256, 0, stream>>>(y, ynb, ln2g, ln2b, F, F);
    transpose_cvt<<<dim3(24, 32, 8), tb, 0, stream>>>(ynb, ynT, 1024, 768, Z);

    // Q = xn @ wq + bq; K = yn @ wk + bk  (merged: grid z=2 -> 768 blocks)
    gemm_qk<<<dim3(6, 64, 2), 256, 0, stream>>>(xn, ynb, wqT, wkT, qb, kb, bq, bk, F);

    // attention in 6 head-groups of 2:
    //   P = softmax(QK^T/8)  (materialized, 33.5 MB)
    //   T = P @ yn           (batched 128x128-tile MFMA GEMM, K=1024)
    //   dx (+)= T @ W2^T     (K=1536 slice of W2T)
    for (int g = 0; g < 6; ++g) {
        fused_S<<<1024, 512, 0, stream>>>(qb, kb, Pbuf, g);
        gemm_T<<<dim3(6, 8, 16), 256, 0, stream>>>(Pbuf, ynT, Tb2);
        gemm_acc<<<dim3(6, 64), 256, 0, stream>>>(Tb2, W2T + g * 1536, dxf,
                                                  1536, 1536, 9216, 768, g == 0);
    }

    // h_pre = xn + dx + sum_h bv_h   (qb dead -> reuse)
    hpre_ep<<<24576, 256, 0, stream>>>(dxf, bvs, xn, hpre);

    ln768<<<8192, 256, 0, stream>>>(hpre, hn, ln3g, ln3b, Z, F);

    gemm_bt<<<dim3(6, 64), 256, 0, stream>>>(hn, wiT, mid, 768, 768, 768, 768,
                                             bi, F, nullptr, 1);
    gemm_bt<<<dim3(6, 64), 256, 0, stream>>>(mid, woT, res0, 768, 768, 768, 768,
                                             bo, F, hn, 0);

    emit2<<<2048, 256, 0, stream>>>(res0, ynb, d_out, F);
}

// Round 3
// 897.931 us; speedup vs baseline: 1.9667x; 1.1866x over previous
//
#include <hip/hip_runtime.h>
#include <hip/hip_bf16.h>
#include <stdint.h>

// Inputs may be float32 OR bf16 (detected at runtime on-device); internal
// canonical dtype is bf16; compute in fp32; output emitted in detected dtype.
typedef __bf16 bf16_t;
typedef __bf16 bf16x8 __attribute__((ext_vector_type(8)));
typedef float  f32x4  __attribute__((ext_vector_type(4)));

typedef __attribute__((address_space(3))) unsigned int lds_u32;
typedef const __attribute__((address_space(1))) unsigned int glob_u32;
#define GLDS16(g, l) __builtin_amdgcn_global_load_lds((glob_u32*)(g), (lds_u32*)(l), 16, 0, 0)

__device__ __forceinline__ f32x4 mfma16(bf16x8 a, bf16x8 b, f32x4 c) {
    // D[row=quad*4+r][col=lane&15]; A[row=lane&15][k=quad*8+j]; B[k=quad*8+j][col=lane&15]
    return __builtin_amdgcn_mfma_f32_16x16x32_bf16(a, b, c, 0, 0, 0);
}

__device__ __forceinline__ float ldv(const void* p, long i, int fp32mode) {
    return fp32mode ? ((const float*)p)[i] : (float)((const bf16_t*)p)[i];
}

// ---------------------------------------------------------------- dtype detect
__global__ __launch_bounds__(256)
void detect_dtype(const void* __restrict__ x, int* __restrict__ flag) {
    __shared__ int cnt;
    if (threadIdx.x == 0) cnt = 0;
    __syncthreads();
    const bf16_t* p = (const bf16_t*)x;
    int local = 0;
    for (int i = threadIdx.x; i < 4096; i += 256) {
        const float v = (float)p[i];
        if (!(fabsf(v) < 1e6f)) local++;   // catches NaN too
    }
    atomicAdd(&cnt, local);
    __syncthreads();
    if (threadIdx.x == 0) { flag[0] = (cnt >= 16) ? 1 : 0; flag[1] = 0; }
}

// ---------------------------------------------------------------- convert-transpose (batched)
__global__ __launch_bounds__(256)
void transpose_cvt(const void* __restrict__ in, bf16_t* __restrict__ out,
                   int R, int C, const int* __restrict__ flagp) {
    __shared__ bf16_t t[32][33];
    const int mode = *flagp;
    const long zi = (long)blockIdx.z * R * C;
    const int c0 = blockIdx.x * 32;
    const int r0 = blockIdx.y * 32;
    const int x  = threadIdx.x;
    const int y0 = threadIdx.y;
    for (int yy = y0; yy < 32; yy += 8)
        t[yy][x] = (bf16_t)ldv(in, zi + (long)(r0 + yy) * C + c0 + x, mode);
    __syncthreads();
    for (int yy = y0; yy < 32; yy += 8)
        out[zi + (long)(c0 + yy) * R + r0 + x] = t[x][yy];
}

// ---------------------------------------------------------------- wv permuted transpose
// W2T[e][h*768+k] = wv[k][h*768+e]   (both ld 9216)
__global__ __launch_bounds__(256)
void transpose_wv(const void* __restrict__ in, bf16_t* __restrict__ out,
                  const int* __restrict__ flagp) {
    __shared__ bf16_t t[32][33];
    const int mode = *flagp;
    const int h  = blockIdx.z;
    const int e0 = blockIdx.x * 32;
    const int k0 = blockIdx.y * 32;
    const int x  = threadIdx.x;
    const int y0 = threadIdx.y;
    for (int yy = y0; yy < 32; yy += 8)
        t[yy][x] = (bf16_t)ldv(in, (long)(k0 + yy) * 9216 + h * 768 + e0 + x, mode);
    __syncthreads();
    for (int yy = y0; yy < 32; yy += 8)
        out[(long)(e0 + yy) * 9216 + h * 768 + k0 + x] = t[x][yy];
}

// ---------------------------------------------------------------- bv head-sum
__global__ __launch_bounds__(256)
void bvsum_k(const void* __restrict__ bv, float* __restrict__ out,
             const int* __restrict__ flagp) {
    const int mode = *flagp;
    const int e = blockIdx.x * 256 + threadIdx.x;
    if (e < 768) {
        float s = 0.f;
#pragma unroll
        for (int h = 0; h < 12; ++h) s += ldv(bv, h * 768 + e, mode);
        out[e] = s;
    }
}

// ---------------------------------------------------------------- layernorm (768 cols)
__global__ __launch_bounds__(256)
void ln768(const void* __restrict__ in, bf16_t* __restrict__ out,
           const void* __restrict__ gam, const void* __restrict__ bet,
           const int* __restrict__ dmodep, const int* __restrict__ pmodep) {
    __shared__ float rs[256], rq[256];
    const int dm = *dmodep, pm = *pmodep;
    const long base = (long)blockIdx.x * 768;
    const int tid = threadIdx.x;
    float v[3];
    float s = 0.f, q = 0.f;
#pragma unroll
    for (int i = 0; i < 3; ++i) {
        v[i] = ldv(in, base + i * 256 + tid, dm);
        s += v[i];
        q += v[i] * v[i];
    }
    rs[tid] = s; rq[tid] = q;
    __syncthreads();
    for (int st = 128; st > 0; st >>= 1) {
        if (tid < st) { rs[tid] += rs[tid + st]; rq[tid] += rq[tid + st]; }
        __syncthreads();
    }
    const float mean = rs[0] * (1.0f / 768.0f);
    const float var  = rq[0] * (1.0f / 768.0f) - mean * mean;
    const float rstd = rsqrtf(var + 1e-5f);
#pragma unroll
    for (int i = 0; i < 3; ++i) {
        const int c = i * 256 + tid;
        out[base + c] = (bf16_t)((v[i] - mean) * rstd * ldv(gam, c, pm) + ldv(bet, c, pm));
    }
}

// ================================================================ GEMM common
// 128 x (JN*32) tile, BK=64, linear LDS staged via global_load_lds width-16
// with both-sides XOR swizzle (byte ^= (row&7)<<4): conflict-free ds_read_b128.
// 2-phase double-buffered: stage(t+1) issued before MFMA(t), one barrier/step.
// JN=3 -> BN=96 (exact-fill 512-block grids for the N=768 GEMMs); JN=4 -> BN=128.
#define BK 64
#define TILEA 16384   // bytes per [128][64] bf16 tile

template<int JN>
__device__ __forceinline__ void stage_ab(const bf16_t* Az, const bf16_t* Bz,
                                         int lda, int ldb, int k0,
                                         char* lA, char* lB, int tid) {
    const int srow = tid >> 3;
    const int sc   = ((tid & 7) * 16) ^ ((srow & 7) << 4);  // row&7 invariant in p
#pragma unroll
    for (int p = 0; p < 4; ++p)
        GLDS16((const char*)(Az + (long)(srow + p * 32) * lda + k0) + sc, lA + p * 4096);
#pragma unroll
    for (int p = 0; p < JN; ++p)
        GLDS16((const char*)(Bz + (long)(srow + p * 32) * ldb + k0) + sc, lB + p * 4096);
}

template<int JN>
__device__ __forceinline__ void compute_tile(const char* As, const char* Bs,
                                             int wm, int wn, int l15, int quad,
                                             f32x4 (&acc)[4][JN]) {
#pragma unroll
    for (int kk = 0; kk < BK; kk += 32) {
        bf16x8 af[4], bfr[JN];
        const int cb = kk * 2 + quad * 16;
#pragma unroll
        for (int i = 0; i < 4; ++i) {
            const int r = wm + i * 16 + l15;
            af[i] = *(const bf16x8*)(As + r * 128 + (cb ^ ((r & 7) << 4)));
        }
#pragma unroll
        for (int j = 0; j < JN; ++j) {
            const int r = wn + j * 16 + l15;
            bfr[j] = *(const bf16x8*)(Bs + r * 128 + (cb ^ ((r & 7) << 4)));
        }
#pragma unroll
        for (int i = 0; i < 4; ++i)
#pragma unroll
            for (int j = 0; j < JN; ++j)
                acc[i][j] = mfma16(af[i], bfr[j], acc[i][j]);
    }
}

template<int JN>
__device__ __forceinline__ void kloop(const bf16_t* Az, const bf16_t* Bz,
                                      int K, int lda, int ldb, int tid,
                                      char* AsB, char* BsB,
                                      int wm, int wn, int l15, int quad,
                                      f32x4 (&acc)[4][JN]) {
    const int TILEB = JN * 4096;
    char* lA = AsB + (tid >> 6) * 1024;   // wave-uniform
    char* lB = BsB + (tid >> 6) * 1024;
    int cur = 0;
    stage_ab<JN>(Az, Bz, lda, ldb, 0, lA, lB, tid);
    __syncthreads();
    const int NT = K >> 6;
    for (int t = 0; t < NT - 1; ++t) {
        const int nb = cur ^ 1;
        stage_ab<JN>(Az, Bz, lda, ldb, (t + 1) << 6, lA + nb * TILEA, lB + nb * TILEB, tid);
        compute_tile<JN>(AsB + cur * TILEA, BsB + cur * TILEB, wm, wn, l15, quad, acc);
        __syncthreads();
        cur = nb;
    }
    compute_tile<JN>(AsB + cur * TILEA, BsB + cur * TILEB, wm, wn, l15, quad, acc);
}

// bijective XCD chunk swizzle over nwg blocks (nwg % 8 == 0)
__device__ __forceinline__ int xcd_swz(int lin, int nwg) {
    return (lin & 7) * (nwg >> 3) + (lin >> 3);
}

// ---------------------------------------------------------------- generic GEMM C = A*B^T (bf16), BN=96
// grid (8, 64): M=8192, N=768 -> 512 blocks = exactly 2/CU, zero tail.
__global__ __launch_bounds__(256, 2)
void gemm_bt(const bf16_t* __restrict__ A, const bf16_t* __restrict__ B,
             bf16_t* __restrict__ C,
             int K, int lda, int ldb, int ldc,
             const void* __restrict__ bias, const int* __restrict__ flagp,
             const bf16_t* __restrict__ res, int do_relu) {
    __shared__ char AsB[2 * TILEA];
    __shared__ char BsB[2 * 3 * 4096];
    const int bmode = *flagp;
    const int swz = xcd_swz(blockIdx.y * 8 + blockIdx.x, 512);
    const int n0 = (swz & 7) * 96;
    const int m0 = (swz >> 3) * 128;
    const bf16_t* Az = A + (long)m0 * lda;
    const bf16_t* Bz = B + (long)n0 * ldb;

    const int tid  = threadIdx.x;
    const int lane = tid & 63;
    const int w    = tid >> 6;
    const int wm   = (w >> 1) * 64;
    const int wn   = (w & 1) * 48;
    const int l15  = lane & 15;
    const int quad = lane >> 4;

    const f32x4 fz = {0.f, 0.f, 0.f, 0.f};
    f32x4 acc[4][3];
#pragma unroll
    for (int i = 0; i < 4; ++i)
#pragma unroll
        for (int j = 0; j < 3; ++j) acc[i][j] = fz;

    kloop<3>(Az, Bz, K, lda, ldb, tid, AsB, BsB, wm, wn, l15, quad, acc);

#pragma unroll
    for (int i = 0; i < 4; ++i) {
#pragma unroll
        for (int j = 0; j < 3; ++j) {
            const int mb = m0 + wm + i * 16 + quad * 4;
            const int nc = n0 + wn + j * 16 + l15;
#pragma unroll
            for (int r = 0; r < 4; ++r) {
                float v = acc[i][j][r];
                if (bias) v += ldv(bias, nc, bmode);
                if (do_relu) v = fmaxf(v, 0.0f);
                if (res) v += (float)res[(long)(mb + r) * ldc + nc];
                C[(long)(mb + r) * ldc + nc] = (bf16_t)v;
            }
        }
    }
}

// ---------------------------------------------------------------- merged Q/K projection (BN=96)
__global__ __launch_bounds__(256, 2)
void gemm_qk(const bf16_t* __restrict__ xn, const bf16_t* __restrict__ ynb,
             const bf16_t* __restrict__ wqT, const bf16_t* __restrict__ wkT,
             bf16_t* __restrict__ qb, bf16_t* __restrict__ kb,
             const void* __restrict__ bq, const void* __restrict__ bk,
             const int* __restrict__ flagp) {
    __shared__ char AsB[2 * TILEA];
    __shared__ char BsB[2 * 3 * 4096];
    const int bmode = *flagp;
    const int z = blockIdx.z;
    const bf16_t* A = z ? ynb : xn;
    const bf16_t* B = z ? wkT : wqT;
    bf16_t*       C = z ? kb  : qb;
    const void* bias = z ? bk : bq;
    const int swz = xcd_swz(blockIdx.y * 8 + blockIdx.x, 512);
    const int n0 = (swz & 7) * 96;
    const int m0 = (swz >> 3) * 128;
    const bf16_t* Az = A + (long)m0 * 768;
    const bf16_t* Bz = B + (long)n0 * 768;

    const int tid  = threadIdx.x;
    const int lane = tid & 63;
    const int w    = tid >> 6;
    const int wm   = (w >> 1) * 64;
    const int wn   = (w & 1) * 48;
    const int l15  = lane & 15;
    const int quad = lane >> 4;

    const f32x4 fz = {0.f, 0.f, 0.f, 0.f};
    f32x4 acc[4][3];
#pragma unroll
    for (int i = 0; i < 4; ++i)
#pragma unroll
        for (int j = 0; j < 3; ++j) acc[i][j] = fz;

    kloop<3>(Az, Bz, 768, 768, 768, tid, AsB, BsB, wm, wn, l15, quad, acc);

#pragma unroll
    for (int i = 0; i < 4; ++i) {
#pragma unroll
        for (int j = 0; j < 3; ++j) {
            const int mb = m0 + wm + i * 16 + quad * 4;
            const int nc = n0 + wn + j * 16 + l15;
#pragma unroll
            for (int r = 0; r < 4; ++r)
                C[(long)(mb + r) * 768 + nc] = (bf16_t)(acc[i][j][r] + ldv(bias, nc, bmode));
        }
    }
}

// ---------------------------------------------------------------- VT GEMM (BN=128)
// VTcat[b][e][hc*1024+m] = sum_k ynb[b,m][k] * W2T[e][(h0+hc)*768+k]   (= (yn@wv_h)^T)
// grid (8, 6, 8*G); in-kernel linear remap gives each XCD one batch b
// (ynb_b = 1.5 MB -> L2-resident) regardless of HW z-ordering.
__global__ __launch_bounds__(256, 2)
void gemm_vt(const bf16_t* __restrict__ W2T, const bf16_t* __restrict__ ynb,
             bf16_t* __restrict__ VTc, int h0, int ldP) {
    __shared__ char AsB[2 * TILEA];
    __shared__ char BsB[2 * 4 * 4096];
    const int L  = blockIdx.z * 48 + blockIdx.y * 8 + blockIdx.x;
    const int b  = L & 7;
    const int rest = L >> 3;
    const int hc = rest / 48;
    const int t  = rest % 48;
    const int e0  = (t >> 3) * 128;   // e-rows (6 tiles)
    const int mc0 = (t & 7) * 128;    // m-cols (8 tiles)
    const bf16_t* Az = W2T + (long)e0 * 9216 + (h0 + hc) * 768;
    const bf16_t* Bz = ynb + ((long)b * 1024 + mc0) * 768;

    const int tid  = threadIdx.x;
    const int lane = tid & 63;
    const int w    = tid >> 6;
    const int wm   = (w >> 1) * 64;
    const int wn   = (w & 1) * 64;
    const int l15  = lane & 15;
    const int quad = lane >> 4;

    const f32x4 fz = {0.f, 0.f, 0.f, 0.f};
    f32x4 acc[4][4];
#pragma unroll
    for (int i = 0; i < 4; ++i)
#pragma unroll
        for (int j = 0; j < 4; ++j) acc[i][j] = fz;

    kloop<4>(Az, Bz, 768, 9216, 768, tid, AsB, BsB, wm, wn, l15, quad, acc);

    bf16_t* C = VTc + (long)b * 768 * ldP + (long)hc * 1024;
#pragma unroll
    for (int i = 0; i < 4; ++i) {
#pragma unroll
        for (int j = 0; j < 4; ++j) {
            const int er = e0 + wm + i * 16 + quad * 4;
            const int mc = mc0 + wn + j * 16 + l15;
#pragma unroll
            for (int r = 0; r < 4; ++r)
                C[(long)(er + r) * ldP + mc] = (bf16_t)acc[i][j][r];
        }
    }
}

// ---------------------------------------------------------------- dx GEMM (BN=96), K = G*1024 deep
// dx_b = Pcat_b @ VTcat_b^T; epilogue fuses + dxf(prev passes) + xn + bvs -> hpre.
// mode: 0 first(write dxf), 1 mid(dxf+=), 2 last(hp=dxf+acc+xn+bvs), 3 only(hp=acc+xn+bvs)
// grid (8, 8, 8) = 512 blocks: all resident (2/CU), single round, 192 K-steps at G=12.
__global__ __launch_bounds__(256, 2)
void gemm_dx(const bf16_t* __restrict__ P, const bf16_t* __restrict__ VTc,
             float* __restrict__ dxf, const bf16_t* __restrict__ xnb,
             const float* __restrict__ bvs, bf16_t* __restrict__ hp,
             int ldP, int mode) {
    __shared__ char AsB[2 * TILEA];
    __shared__ char BsB[2 * 3 * 4096];
    const int L = blockIdx.z * 64 + blockIdx.y * 8 + blockIdx.x;
    const int b = L & 7;              // XCD <-> batch affinity
    const int t = L >> 3;
    const int m0 = (t >> 3) * 128;    // n-rows
    const int n0 = (t & 7) * 96;      // e-cols
    const bf16_t* Az = P   + ((long)b * 1024 + m0) * ldP;
    const bf16_t* Bz = VTc + ((long)b * 768  + n0) * ldP;

    const int tid  = threadIdx.x;
    const int lane = tid & 63;
    const int w    = tid >> 6;
    const int wm   = (w >> 1) * 64;
    const int wn   = (w & 1) * 48;
    const int l15  = lane & 15;
    const int quad = lane >> 4;

    const f32x4 fz = {0.f, 0.f, 0.f, 0.f};
    f32x4 acc[4][3];
#pragma unroll
    for (int i = 0; i < 4; ++i)
#pragma unroll
        for (int j = 0; j < 3; ++j) acc[i][j] = fz;

    kloop<3>(Az, Bz, ldP, ldP, ldP, tid, AsB, BsB, wm, wn, l15, quad, acc);

#pragma unroll
    for (int i = 0; i < 4; ++i) {
#pragma unroll
        for (int j = 0; j < 3; ++j) {
            const int gr = b * 1024 + m0 + wm + i * 16 + quad * 4;
            const int nc = n0 + wn + j * 16 + l15;
#pragma unroll
            for (int r = 0; r < 4; ++r) {
                const long gi = (long)(gr + r) * 768 + nc;
                float v = acc[i][j][r];
                if (mode == 1 || mode == 2) v += dxf[gi];
                if (mode <= 1) dxf[gi] = v;
                else hp[gi] = (bf16_t)(v + bvs[nc] + (float)xnb[gi]);
            }
        }
    }
}

// ---------------------------------------------------------------- fused S -> softmax -> P (cat layout)
// Per (b, 16-row n-tile, head hc of this pass): S = Q K^T / 8 (full M=1024 in
// regs; 8 col-waves), exact softmax, P -> LDS -> coalesced store to
// Pcat[b*1024+n][hc*1024+m], ld ldP. Grid x = 512*G; b = bx&7 (XCD affinity).
__global__ __launch_bounds__(512, 8)
void fused_S(const bf16_t* __restrict__ Q, const bf16_t* __restrict__ Kp,
             bf16_t* __restrict__ P, int h0, int ldP) {
    __shared__ bf16_t Pl[16][1032];
    __shared__ float  rmax[8][16];
    __shared__ float  rsum[8][16];

    const int bx   = blockIdx.x;
    const int b    = bx & 7;
    const int n0   = ((bx >> 3) & 63) * 16;
    const int hc   = bx >> 9;           // head within pass
    const int h    = h0 + hc;           // global head
    const int tid  = threadIdx.x;
    const int w    = tid >> 6;          // 0..7 col-waves
    const int lane = tid & 63;
    const int l15  = lane & 15;
    const int quad = lane >> 4;

    const f32x4 fz = {0.f, 0.f, 0.f, 0.f};
    const long qoff = (long)(b * 1024 + n0 + l15) * 768 + h * 64 + quad * 8;
    const long koff = (long)(b * 1024) * 768 + h * 64 + quad * 8;

    // ---- S = Q K^T: this wave covers cols m = w*128 + f*16 + l15
    f32x4 s[8];
#pragma unroll
    for (int f = 0; f < 8; ++f) s[f] = fz;
    const bf16x8 qa0 = *(const bf16x8*)(Q + qoff);
    const bf16x8 qa1 = *(const bf16x8*)(Q + qoff + 32);
#pragma unroll
    for (int f = 0; f < 8; ++f) {
        const int m = w * 128 + f * 16 + l15;
        const bf16_t* kp = Kp + koff + (long)m * 768;
        s[f] = mfma16(qa0, *(const bf16x8*)kp, s[f]);
        s[f] = mfma16(qa1, *(const bf16x8*)(kp + 32), s[f]);
    }
    // ---- softmax over m; lane owns rows quad*4 + r
    float rm[4] = {-3e38f, -3e38f, -3e38f, -3e38f};
#pragma unroll
    for (int f = 0; f < 8; ++f)
#pragma unroll
        for (int r = 0; r < 4; ++r) {
            s[f][r] *= 0.125f;
            rm[r] = fmaxf(rm[r], s[f][r]);
        }
#pragma unroll
    for (int off = 1; off < 16; off <<= 1)
#pragma unroll
        for (int r = 0; r < 4; ++r) rm[r] = fmaxf(rm[r], __shfl_xor(rm[r], off));
    if (l15 == 0) {
#pragma unroll
        for (int r = 0; r < 4; ++r) rmax[w][quad * 4 + r] = rm[r];
    }
    __syncthreads();
    float gm[4];
#pragma unroll
    for (int r = 0; r < 4; ++r) {
        float mx = rmax[0][quad * 4 + r];
#pragma unroll
        for (int w2 = 1; w2 < 8; ++w2) mx = fmaxf(mx, rmax[w2][quad * 4 + r]);
        gm[r] = mx;
    }
    float ps[4] = {0.f, 0.f, 0.f, 0.f};
#pragma unroll
    for (int f = 0; f < 8; ++f)
#pragma unroll
        for (int r = 0; r < 4; ++r) {
            const float p = __expf(s[f][r] - gm[r]);
            s[f][r] = p;
            ps[r] += p;
        }
#pragma unroll
    for (int off = 1; off < 16; off <<= 1)
#pragma unroll
        for (int r = 0; r < 4; ++r) ps[r] += __shfl_xor(ps[r], off);
    if (l15 == 0) {
#pragma unroll
        for (int r = 0; r < 4; ++r) rsum[w][quad * 4 + r] = ps[r];
    }
    __syncthreads();
#pragma unroll
    for (int r = 0; r < 4; ++r) {
        float ss = 0.f;
#pragma unroll
        for (int w2 = 0; w2 < 8; ++w2) ss += rsum[w2][quad * 4 + r];
        gm[r] = 1.0f / ss;
    }
#pragma unroll
    for (int f = 0; f < 8; ++f)
#pragma unroll
        for (int r = 0; r < 4; ++r)
            Pl[quad * 4 + r][w * 128 + f * 16 + l15] = (bf16_t)(s[f][r] * gm[r]);
    __syncthreads();

    // ---- coalesced store of the 16x1024 P tile (32 threads per row)
    const long pbase = ((long)b * 1024 + n0) * ldP + (long)hc * 1024;
    const int rr = tid >> 5;
    const int c0 = (tid & 31) * 32;
    bf16_t* dst = P + pbase + (long)rr * ldP + c0;
#pragma unroll
    for (int u = 0; u < 4; ++u)
        *(bf16x8*)(dst + u * 8) = *(const bf16x8*)(&Pl[rr][c0 + u * 8]);
}

// ---------------------------------------------------------------- output emit
__global__ __launch_bounds__(256)
void emit2(const bf16_t* __restrict__ a, const bf16_t* __restrict__ b,
           void* __restrict__ out, const int* __restrict__ flagp) {
    const int mode = *flagp;
    const long n = 6291456;
    const long stride = (long)gridDim.x * blockDim.x;
    for (long i = (long)blockIdx.x * blockDim.x + threadIdx.x; i < 2 * n; i += stride) {
        const bf16_t v = (i < n) ? a[i] : b[i - n];
        if (mode) ((float*)out)[i] = (float)v;
        else      ((bf16_t*)out)[i] = v;
    }
}

// ---------------------------------------------------------------- launch
extern "C" void kernel_launch(void* const* d_in, const int* in_sizes, int n_in,
                              void* d_out, int out_size, void* d_ws, size_t ws_size,
                              hipStream_t stream) {
    (void)in_sizes; (void)n_in; (void)out_size;

    const void* x    = d_in[0];
    const void* y    = d_in[1];
    const void* ln1g = d_in[2];
    const void* ln1b = d_in[3];
    const void* ln2g = d_in[4];
    const void* ln2b = d_in[5];
    const void* ln3g = d_in[6];
    const void* ln3b = d_in[7];
    const void* wq   = d_in[8];
    const void* bq   = d_in[9];
    const void* wk   = d_in[10];
    const void* bk   = d_in[11];
    const void* wv   = d_in[12];
    const void* bv   = d_in[13];
    const void* wi   = d_in[14];
    const void* bi   = d_in[15];
    const void* wo   = d_in[16];
    const void* bo   = d_in[17];

    // ---- workspace layout (canonical bf16 unless noted) ----
    // fixed block = 94,380,032 B; per-pass block = G*(16,777,216 + 12,582,912).
    // G (heads per pass) chosen from ws_size; G=2 floor needs 153.1 MB (< the
    // 165.7 MB the previous passing kernel already used).
    char* ws = (char*)d_ws;
    bf16_t* xn    = (bf16_t*)(ws + 0);           // 12,582,912 (later res0)
    bf16_t* ynb   = (bf16_t*)(ws + 12582912);    // 12,582,912 (output 1)
    bf16_t* qb    = (bf16_t*)(ws + 25165824);    // 12,582,912 (Q; later h_pre)
    bf16_t* kb    = (bf16_t*)(ws + 37748736);    // 12,582,912 (K; later hn)
    bf16_t* W2T   = (bf16_t*)(ws + 50331648);    // 14,155,776
    bf16_t* wqT   = (bf16_t*)(ws + 64487424);    // 1,179,648
    bf16_t* wkT   = (bf16_t*)(ws + 65667072);
    bf16_t* wiT   = (bf16_t*)(ws + 66846720);
    bf16_t* woT   = (bf16_t*)(ws + 68026368);
    float*  bvs   = (float*) (ws + 69206016);    // 3,072
    int*    flag  = (int*)   (ws + 69210112);    // flag[0]=fp32 mode, flag[1]=0
    float*  dxf   = (float*) (ws + 69214208);    // 25,165,824 (multi-pass only)

    static const int GS[5] = {12, 6, 4, 3, 2};
    int G = 2;
    for (int i = 0; i < 5; ++i) {
        const unsigned long long need =
            94380032ULL + (unsigned long long)GS[i] * 29360128ULL;
        if (need <= (unsigned long long)ws_size) { G = GS[i]; break; }
    }
    const int ldP = G * 1024;
    bf16_t* Pcat = (bf16_t*)(ws + 94380032);                            // G*16,777,216
    bf16_t* VTc  = (bf16_t*)(ws + 94380032 + (size_t)G * 16777216);     // G*12,582,912
    bf16_t* hpre = qb;
    bf16_t* hn   = kb;
    bf16_t* mid  = Pcat;     // 12.6 MB, reused after attention
    bf16_t* res0 = xn;
    const int* F = flag;
    const int* Z = flag + 1;

    detect_dtype<<<1, 256, 0, stream>>>(x, flag);

    const dim3 tb(32, 8);
    transpose_cvt<<<dim3(24, 24, 1), tb, 0, stream>>>(wq, wqT, 768, 768, F);
    transpose_cvt<<<dim3(24, 24, 1), tb, 0, stream>>>(wk, wkT, 768, 768, F);
    transpose_cvt<<<dim3(24, 24, 1), tb, 0, stream>>>(wi, wiT, 768, 768, F);
    transpose_cvt<<<dim3(24, 24, 1), tb, 0, stream>>>(wo, woT, 768, 768, F);
    transpose_wv<<<dim3(24, 24, 12), tb, 0, stream>>>(wv, W2T, F);
    bvsum_k<<<3, 256, 0, stream>>>(bv, bvs, F);

    ln768<<<8192, 256, 0, stream>>>(x, xn, ln1g, ln1b, F, F);
    ln768<<<8192, 256, 0, stream>>>(y, ynb, ln2g, ln2b, F, F);

    // Q = xn @ wq + bq; K = yn @ wk + bk  (1024 blocks, 2 exact rounds)
    gemm_qk<<<dim3(8, 64, 2), 256, 0, stream>>>(xn, ynb, wqT, wkT, qb, kb, bq, bk, F);

    // attention middle, cat-K route:
    //   Pcat[b][n][hc*1024+m] = softmax(Q K^T / 8)
    //   VTcat[b][e][hc*1024+m] = (yn @ wv_h)^T   (from W2T, no transpose pass)
    //   dx_b = Pcat_b @ VTcat_b^T  (K = G*1024 deep; epilogue -> h_pre)
    const int npass = 12 / G;
    for (int p = 0; p < npass; ++p) {
        const int h0 = p * G;
        fused_S<<<512 * G, 512, 0, stream>>>(qb, kb, Pcat, h0, ldP);
        gemm_vt<<<dim3(8, 6, 8 * G), 256, 0, stream>>>(W2T, ynb, VTc, h0, ldP);
        const int mode = (npass == 1) ? 3 : (p == 0 ? 0 : (p == npass - 1 ? 2 : 1));
        gemm_dx<<<dim3(8, 8, 8), 256, 0, stream>>>(Pcat, VTc, dxf, xn, bvs, hpre,
                                                   ldP, mode);
    }

    ln768<<<8192, 256, 0, stream>>>(hpre, hn, ln3g, ln3b, Z, F);

    gemm_bt<<<dim3(8, 64), 256, 0, stream>>>(hn, wiT, mid, 768, 768, 768, 768,
                                             bi, F, nullptr, 1);
    gemm_bt<<<dim3(8, 64), 256, 0, stream>>>(mid, woT, res0, 768, 768, 768, 768,
                                             bo, F, hn, 0);

    emit2<<<2048, 256, 0, stream>>>(res0, ynb, d_out, F);
}